// Round 2
// baseline (524.918 us; speedup 1.0000x reference)
//
#include <hip/hip_runtime.h>
#include <hip/hip_bf16.h>

// Problem constants (B,N,C,NF) = (4,512,128,96)
#define NB 4
#define NN 512
#define CC 128

typedef __bf16 bf16x8 __attribute__((ext_vector_type(8)));
typedef __bf16 bf16x4 __attribute__((ext_vector_type(4)));
typedef float  f32x4  __attribute__((ext_vector_type(4)));

// ---------------- fused fp32 -> bf16 conversion (x, w1..w4 in one launch) ----
__global__ void cvt_all(const float* __restrict__ x,  __bf16* __restrict__ xb,
                        const float* __restrict__ w1, __bf16* __restrict__ w1b,
                        const float* __restrict__ w2, __bf16* __restrict__ w2b,
                        const float* __restrict__ w3, __bf16* __restrict__ w3b,
                        const float* __restrict__ w4, __bf16* __restrict__ w4b)
{
    int idx = blockIdx.x * blockDim.x + threadIdx.x;
    const float* s; __bf16* d; int off;
    if      (idx <  65536) { s = x;  d = xb;  off = idx; }           // 262144 f32
    else if (idx <  71680) { s = w1; d = w1b; off = idx -  65536; }  //  24576
    else if (idx <  80896) { s = w2; d = w2b; off = idx -  71680; }  //  36864
    else if (idx <  85504) { s = w3; d = w3b; off = idx -  80896; }  //  18432
    else if (idx <  87808) { s = w4; d = w4b; off = idx -  85504; }  //   9216
    else return;
    float4 v = ((const float4*)s)[off];
    bf16x4 o = { (__bf16)v.x, (__bf16)v.y, (__bf16)v.z, (__bf16)v.w };
    ((bf16x4*)d)[off] = o;
}

// ---------------- one MLP layer via MFMA, orientation h^T = W * act^T -------
// A = weights (global bf16 row-major [NOUT][KIN]): A[m=ch_out][k], contiguous 16B.
// B = act from LDS [edge][ch] (stride SIN, mult of 8): B[k][n=edge] reads
//     act[edge][k..k+7] -> ds_read_b128 contiguous.
// D: lane -> col n = edge (lane&15), rows m = ch_out (lane>>4)*4 + reg:
//     4 CONSECUTIVE channels -> pack lrelu'd bf16x4, ONE ds_write_b64 into
//     out [edge][ch] (stride SOUT).
// WIDE  (NOUT=192): wave w -> m-chunks {w, w+4, w+8}, all 4 edge-tiles
// !WIDE (NOUT= 96): wave w -> m-chunks {(w&1)*3+0..2}, edge-tiles (w>>1)*2..+1
template<int KIN, int SIN, int SOUT, bool WIDE>
__device__ __forceinline__ void mlp_layer(const __bf16* in, __bf16* outb,
                                          const __bf16* __restrict__ w,
                                          const float* __restrict__ bias,
                                          int lane, int wave)
{
    constexpr int KC = KIN / 32;
    const int l15 = lane & 15;
    const int q   = lane >> 4;
    const int q8  = q * 8;
    int mc0, mstep, nlo, nhi;
    if (WIDE) { mc0 = wave;          mstep = 4; nlo = 0;             nhi = 4; }
    else      { mc0 = (wave & 1)*3;  mstep = 1; nlo = (wave >> 1)*2; nhi = nlo + 2; }

    bf16x8 wfr[3][KC];
    f32x4  bv[3];
#pragma unroll
    for (int u = 0; u < 3; ++u) {
        const int ch = (mc0 + u * mstep) * 16;
        bv[u] = *(const f32x4*)(bias + ch + q * 4);   // bias per out-channel (D rows)
#pragma unroll
        for (int k = 0; k < KC; ++k)
            wfr[u][k] = *(const bf16x8*)(w + (size_t)(ch + l15) * KIN + k * 32 + q8);
    }

    for (int nt = nlo; nt < nhi; ++nt) {
        f32x4 acc[3];
#pragma unroll
        for (int u = 0; u < 3; ++u) acc[u] = bv[u];
        const __bf16* inrow = in + (nt * 16 + l15) * SIN + q8;
#pragma unroll
        for (int k = 0; k < KC; ++k) {
            bf16x8 bfrag = *(const bf16x8*)(inrow + k * 32);
#pragma unroll
            for (int u = 0; u < 3; ++u)
                acc[u] = __builtin_amdgcn_mfma_f32_16x16x32_bf16(wfr[u][k], bfrag, acc[u], 0, 0, 0);
        }
        __bf16* orow = outb + (nt * 16 + l15) * SOUT;
#pragma unroll
        for (int u = 0; u < 3; ++u) {
            bf16x4 o;
#pragma unroll
            for (int r = 0; r < 4; ++r) {
                float v = acc[u][r];
                v = v > 0.f ? v : 0.01f * v;          // leaky relu
                o[r] = (__bf16)v;
            }
            *(bf16x4*)(orow + (mc0 + u * mstep) * 16 + q * 4) = o;  // ds_write_b64
        }
    }
}

// ---------------- layer4 (96->96) + layer5 (96->1) fully in registers -------
// Narrow split: wave w -> ch-chunks {(w&1)*3+0..2}, edge-tiles (w>>1)*2..+1.
// After L4's MFMA each lane holds 12 channels of ONE edge -> dot with w5 in
// regs, shfl-reduce over quads, tiny LDS combine across the wave pair.
__device__ __forceinline__ void layer45(const __bf16* in /*h3, stride 104*/,
                                        const __bf16* __restrict__ w4,
                                        const float* __restrict__ b4,
                                        const float* __restrict__ w5,
                                        const float* __restrict__ b5,
                                        float* red /*[4][2][16]*/,
                                        int lane, int wave,
                                        int i0, int j0, int bidx,
                                        float* __restrict__ out)
{
    constexpr int KC = 3, SIN = 104;
    const int l15 = lane & 15;
    const int q   = lane >> 4;
    const int q8  = q * 8;
    const int mc0 = (wave & 1) * 3;
    const int nlo = (wave >> 1) * 2;

    bf16x8 wfr[3][KC];
    f32x4  bv[3];
    f32x4  w5v[3];
#pragma unroll
    for (int u = 0; u < 3; ++u) {
        const int ch = (mc0 + u) * 16;
        bv[u]  = *(const f32x4*)(b4 + ch + q * 4);
        w5v[u] = *(const f32x4*)(w5 + ch + q * 4);
#pragma unroll
        for (int k = 0; k < KC; ++k)
            wfr[u][k] = *(const bf16x8*)(w4 + (size_t)(ch + l15) * 96 + k * 32 + q8);
    }

#pragma unroll
    for (int ntl = 0; ntl < 2; ++ntl) {
        const int nt = nlo + ntl;
        f32x4 acc[3];
#pragma unroll
        for (int u = 0; u < 3; ++u) acc[u] = bv[u];
        const __bf16* inrow = in + (nt * 16 + l15) * SIN + q8;
#pragma unroll
        for (int k = 0; k < KC; ++k) {
            bf16x8 bfrag = *(const bf16x8*)(inrow + k * 32);
#pragma unroll
            for (int u = 0; u < 3; ++u)
                acc[u] = __builtin_amdgcn_mfma_f32_16x16x32_bf16(wfr[u][k], bfrag, acc[u], 0, 0, 0);
        }
        float p = 0.f;
#pragma unroll
        for (int u = 0; u < 3; ++u)
#pragma unroll
            for (int r = 0; r < 4; ++r) {
                float v = acc[u][r];
                v = v > 0.f ? v : 0.01f * v;
                p += v * w5v[u][r];
            }
        p += __shfl_xor(p, 16, 64);   // sum over the 4 quads (k-parts of w5 dot)
        p += __shfl_xor(p, 32, 64);
        if (q == 0) red[(wave * 2 + ntl) * 16 + l15] = p;
    }
    __syncthreads();
    if ((wave & 1) == 0 && lane < 32) {
        const int ntl = lane >> 4;
        const int e   = lane & 15;
        const float logit = red[(wave * 2 + ntl) * 16 + e]
                          + red[((wave + 1) * 2 + ntl) * 16 + e] + b5[0];
        const int i = i0 + (wave >> 1) * 2 + ntl;
        const int j = j0 + e;
        out[(((size_t)bidx * NN + i) * NN + j) * 2 + 1] = logit;
    }
}

// ---------------- fused edge-MLP kernel -------------------------------------
// block: 64 edges = 4 i-rows x 16 j, 256 threads (4 waves)
// LDS ping-pong: Abuf: d(136)/h2(200); Bbuf: h1(200)/h3(104)
__global__ __launch_bounds__(256, 3) void mlp_edges(
    const __bf16* __restrict__ xb,
    const __bf16* __restrict__ w1b, const float* __restrict__ b1,
    const __bf16* __restrict__ w2b, const float* __restrict__ b2,
    const __bf16* __restrict__ w3b, const float* __restrict__ b3,
    const __bf16* __restrict__ w4b, const float* __restrict__ b4,
    const float* __restrict__ w5,  const float* __restrict__ b5,
    float* __restrict__ out)
{
    __shared__ __align__(16) __bf16 Abuf[64 * 200];
    __shared__ __align__(16) __bf16 Bbuf[64 * 200];
    __shared__ float red[128];

    const int t    = threadIdx.x;
    const int lane = t & 63;
    const int wave = t >> 6;
    const int j0 = blockIdx.x * 16;
    const int i0 = blockIdx.y * 4;
    const int b  = blockIdx.z;

    // ---- stage d = |x_i - x_j| into Abuf (stride 136) as bf16 ----
    {
        const int m  = t >> 2;            // edge 0..63; i_local = m>>4, j_local = m&15
        const int c0 = (t & 3) * 32;
        const __bf16* xi = xb + ((size_t)b * NN + (i0 + (m >> 4))) * CC;
        const __bf16* xj = xb + ((size_t)b * NN + (j0 + (m & 15))) * CC;
#pragma unroll
        for (int c = 0; c < 32; c += 8) {
            bf16x8 a  = *(const bf16x8*)(xi + c0 + c);
            bf16x8 bj = *(const bf16x8*)(xj + c0 + c);
            bf16x8 dd;
#pragma unroll
            for (int u = 0; u < 8; ++u) {
                float v = (float)a[u] - (float)bj[u];
                dd[u] = (__bf16)fabsf(v);
            }
            *(bf16x8*)(&Abuf[m * 136 + c0 + c]) = dd;
        }
    }
    __syncthreads();
    mlp_layer<128, 136, 200, true >(Abuf, Bbuf, w1b, b1, lane, wave);  // d  -> h1
    __syncthreads();
    mlp_layer<192, 200, 200, true >(Bbuf, Abuf, w2b, b2, lane, wave);  // h1 -> h2
    __syncthreads();
    mlp_layer<192, 200, 104, false>(Abuf, Bbuf, w3b, b3, lane, wave);  // h2 -> h3
    __syncthreads();
    layer45(Bbuf, w4b, b4, w5, b5, red, lane, wave, i0, j0, b, out);   // h3 -> logit
}

// ---------------- softmax over j per (b,i) row, in place on out -------------
__global__ __launch_bounds__(256) void softmax_rows(float* __restrict__ out)
{
    const int row = blockIdx.x;           // b*512 + i
    const int i   = row & (NN - 1);
    float* base = out + (size_t)row * (NN * 2);
    const int t = threadIdx.x;

    float v0 = base[t * 2 + 1];
    float v1 = base[(t + 256) * 2 + 1];
    if (t == i)       v0 = -__builtin_inff();   // self-edge mask
    if (t + 256 == i) v1 = -__builtin_inff();

    float mx = fmaxf(v0, v1);
#pragma unroll
    for (int off = 32; off; off >>= 1) mx = fmaxf(mx, __shfl_xor(mx, off, 64));
    __shared__ float sm[4], ss[4];
    const int wave = t >> 6, lane = t & 63;
    if (lane == 0) sm[wave] = mx;
    __syncthreads();
    mx = fmaxf(fmaxf(sm[0], sm[1]), fmaxf(sm[2], sm[3]));

    const float e0 = __expf(v0 - mx), e1 = __expf(v1 - mx);
    float s = e0 + e1;
#pragma unroll
    for (int off = 32; off; off >>= 1) s += __shfl_xor(s, off, 64);
    if (lane == 0) ss[wave] = s;
    __syncthreads();
    s = ss[0] + ss[1] + ss[2] + ss[3];
    const float inv = 1.0f / s;

    float2* o2 = (float2*)base;
    o2[t]       = make_float2(t == i ? 1.f : 0.f,         e0 * inv);
    o2[t + 256] = make_float2((t + 256) == i ? 1.f : 0.f, e1 * inv);
}

// ---------------- host launch ----------------
extern "C" void kernel_launch(void* const* d_in, const int* in_sizes, int n_in,
                              void* d_out, int out_size, void* d_ws, size_t ws_size,
                              hipStream_t stream) {
    const float* x  = (const float*)d_in[0];
    // d_in[1] = W_id (pure eye broadcast; synthesized in-kernel)
    const float* w1 = (const float*)d_in[2];
    const float* b1 = (const float*)d_in[3];
    const float* w2 = (const float*)d_in[4];
    const float* b2 = (const float*)d_in[5];
    const float* w3 = (const float*)d_in[6];
    const float* b3 = (const float*)d_in[7];
    const float* w4 = (const float*)d_in[8];
    const float* b4 = (const float*)d_in[9];
    const float* w5 = (const float*)d_in[10];
    const float* b5 = (const float*)d_in[11];
    float* out = (float*)d_out;

    // ws layout (bf16): x 524288B | w1 49152B | w2 73728B | w3 36864B | w4 18432B
    char* ws = (char*)d_ws;
    __bf16* xb  = (__bf16*)(ws);
    __bf16* w1b = (__bf16*)(ws + 524288);
    __bf16* w2b = (__bf16*)(ws + 573440);
    __bf16* w3b = (__bf16*)(ws + 647168);
    __bf16* w4b = (__bf16*)(ws + 684032);

    cvt_all<<<(87808 + 255) / 256, 256, 0, stream>>>(x, xb, w1, w1b, w2, w2b,
                                                     w3, w3b, w4, w4b);

    dim3 grid(NN / 16, NN / 4, NB);   // j-tiles, i-tiles, batch
    mlp_edges<<<grid, 256, 0, stream>>>(xb, w1b, b1, w2b, b2, w3b, b3, w4b, b4,
                                        w5, b5, out);

    softmax_rows<<<NB * NN, 256, 0, stream>>>(out);
}